// Round 7
// baseline (177.361 us; speedup 1.0000x reference)
//
#include <hip/hip_runtime.h>
#include <hip/hip_fp8.h>
#include <math.h>

#define NB 4096
#define IN_D 230
#define DM 256
#define NL 12
#define DST 16
#define DI 512
#define DTR 16
#define XPN 48
#define XB 528    // xcs/szs row stride (bytes), 16-B aligned
#define HB 272    // hs row stride (bytes), 16-B aligned

typedef __attribute__((ext_vector_type(4))) float floatx4;
typedef __attribute__((ext_vector_type(2))) float floatx2;
typedef __attribute__((ext_vector_type(2))) long long2v;
typedef __attribute__((ext_vector_type(4))) int intx4;
typedef __attribute__((ext_vector_type(8))) int intx8;

__device__ __forceinline__ float silu_f(float x) {
    return x * __builtin_amdgcn_rcpf(1.0f + __expf(-x));
}
__device__ __forceinline__ float softplus_f(float x) {
    return (x > 20.0f) ? x : __logf(1.0f + __expf(x));
}

__device__ __forceinline__ unsigned char f2fp8(float x) {
#if __has_builtin(__builtin_amdgcn_cvt_pk_fp8_f32)
    return (unsigned char)(__builtin_amdgcn_cvt_pk_fp8_f32(x, x, 0, false) & 0xff);
#else
    __hip_fp8_e4m3 t(x); return (unsigned char)t.__x;
#endif
}
// pack 4 floats -> 4 fp8 bytes in one dword
__device__ __forceinline__ unsigned pk4fp8(float a, float b, float c, float d) {
    unsigned w = __builtin_amdgcn_cvt_pk_fp8_f32(a, b, 0, false);
    return __builtin_amdgcn_cvt_pk_fp8_f32(c, d, w, true);
}
// decode byte S of dword w as fp8 — S must be a literal-constant selector
template<int S>
__device__ __forceinline__ float fp8sel(unsigned w) {
    return __builtin_amdgcn_cvt_f32_fp8((int)w, S);
}

// e2m1 encode, round-to-nearest (fallback only — HW cvt used when available)
__device__ __forceinline__ unsigned f2fp4(float x) {
    float ax = fabsf(x);
    unsigned s = (x < 0.0f) ? 8u : 0u;
    unsigned m;
    if      (ax < 0.25f) m = 0;
    else if (ax < 0.75f) m = 1;
    else if (ax < 1.25f) m = 2;
    else if (ax < 1.75f) m = 3;
    else if (ax < 2.50f) m = 4;
    else if (ax < 3.50f) m = 5;
    else if (ax < 5.00f) m = 6;
    else                 m = 7;
    return s | m;
}

// ---------- single prep kernel: packs everything + converts x ----------
// Block ranges:
// [0,16)       Wi  -> fp8 fragment chunks (stage 0)
// [16,784)     in_proj  -> fp4 (12 x 64 tiles)
// [784,1168)   out_proj -> fp4 (12 x 32 tiles)
// [1168,1264)  x_proj   -> fp4 (12 x 8 tiles)
// [1264,1456)  dt_w -> fp8 fragments (K=16 pad 32), 4 B/thread packed
// [1456,1480)  cwcb table | [1480,1504) dbdv table
// [1504,2528)  x -> xpad fp8, 4 B/thread packed
// R7: tile loads vectorized to float4 (4 loads/thread instead of 16 scalar);
// tbuf stride 65 -> 68 floats for 16-B alignment.
__global__ __launch_bounds__(256) void pack_all(
    const float* __restrict__ x,
    const float* __restrict__ Wi, const float* __restrict__ ip,
    const float* __restrict__ op, const float* __restrict__ xp,
    const float* __restrict__ dtw,
    const float* __restrict__ cw, const float* __restrict__ cb,
    const float* __restrict__ db, const float* __restrict__ Dv,
    unsigned char* __restrict__ xpad,
    unsigned char* __restrict__ WiT, unsigned char* __restrict__ dtwP,
    unsigned char* __restrict__ ip4, unsigned char* __restrict__ op4,
    unsigned char* __restrict__ xp4,
    floatx2* __restrict__ cwcb, floatx2* __restrict__ dbdv)
{
    __shared__ float tbuf[64][68];
    const int fid = blockIdx.x;

    if (fid < 1264) {
        const float* src; unsigned char* dst;
        int K, N, ngK, t;
        bool isfp4;
        if (fid < 16) {
            src = Wi; dst = WiT; K = IN_D; N = DM; ngK = 4; t = fid; isfp4 = false;
        } else if (fid < 784) {
            int local = fid - 16; int l = local >> 6; t = local & 63;
            K = DM; N = 2 * DI; ngK = 4; isfp4 = true;
            src = ip + (size_t)l * K * N; dst = ip4 + (size_t)l * 131072;
        } else if (fid < 1168) {
            int local = fid - 784; int l = local >> 5; t = local & 31;
            K = DI; N = DM; ngK = 8; isfp4 = true;
            src = op + (size_t)l * K * N; dst = op4 + (size_t)l * 65536;
        } else {
            int local = fid - 1168; int l = local >> 3; t = local & 7;
            K = DI; N = XPN; ngK = 8; isfp4 = true;
            src = xp + (size_t)l * K * N; dst = xp4 + (size_t)l * 16384;
        }
        const int g = t % ngK, nb = t / ngK;
        const int k0 = g * 64, n0 = nb * 64;
        {
            const int t4 = threadIdx.x;
#pragma unroll
            for (int i = 0; i < 4; i++) {
                int fi = i * 256 + t4;           // float4 index in tile (0..1023)
                int lr = fi >> 4;                // local row 0..63
                int lc = (fi & 15) * 4;          // local col 0,4,..60
                int kk = k0 + lr, nn = n0 + lc;
                floatx4 v;
                if (kk < K && nn + 3 < N) {
                    v = *(const floatx4*)(src + (size_t)kk * N + nn);
                } else {
#pragma unroll
                    for (int j = 0; j < 4; j++)
                        v[j] = (kk < K && nn + j < N) ? src[(size_t)kk * N + nn + j] : 0.0f;
                }
                *(floatx4*)(&tbuf[lr][lc]) = v;
            }
        }
        __syncthreads();
        if (!isfp4) {
            // fp8 fragment chunk (16 cols x 64 k -> 1024 B)
            const int cbi = threadIdx.x >> 6;
            const int lane = threadIdx.x & 63;
            const int q = lane >> 4, m16 = lane & 15;
            const int chunk = (nb * 4 + cbi) * ngK + g;
            union { unsigned char b[16]; intx4 v; } buf;
#pragma unroll
            for (int sub = 0; sub < 2; sub++)
#pragma unroll
                for (int byt = 0; byt < 8; byt++) {
                    int k = sub * 32 + q * 8 + byt;
                    int n = cbi * 16 + m16;
                    buf.b[sub * 8 + byt] = f2fp8(tbuf[k][n]);
                }
            *(intx4*)(dst + (size_t)chunk * 1024 + lane * 16) = buf.v;
        } else {
            // fp4 fragment half-chunk: tile = k-group g (64 wide) of fp4 chunk kg=g>>1
            const int kg = g >> 1, half = g & 1;
            const int nkg128 = ngK >> 1;
            const int cbi = threadIdx.x >> 6;          // 0..3
            const int rem = threadIdx.x & 63;
            const int q4loc = rem >> 5;                // 0..1
            const int hb = (rem >> 4) & 1;             // 0..1
            const int m16 = rem & 15;
            const int q4 = half * 2 + q4loc;
            const int chunk = (nb * 4 + cbi) * nkg128 + kg;
            const int kb = q4loc * 32 + hb * 16;
            const int nn = cbi * 16 + m16;
            union { unsigned u[2]; long v; } buf;
#if __has_builtin(__builtin_amdgcn_cvt_scalef32_pk_fp4_f32)
            unsigned d0 = 0, d1 = 0;
            d0 = __builtin_amdgcn_cvt_scalef32_pk_fp4_f32(d0, tbuf[kb + 0][nn] * 128.0f, tbuf[kb + 1][nn] * 128.0f, 1.0f, 0);
            d0 = __builtin_amdgcn_cvt_scalef32_pk_fp4_f32(d0, tbuf[kb + 2][nn] * 128.0f, tbuf[kb + 3][nn] * 128.0f, 1.0f, 1);
            d0 = __builtin_amdgcn_cvt_scalef32_pk_fp4_f32(d0, tbuf[kb + 4][nn] * 128.0f, tbuf[kb + 5][nn] * 128.0f, 1.0f, 2);
            d0 = __builtin_amdgcn_cvt_scalef32_pk_fp4_f32(d0, tbuf[kb + 6][nn] * 128.0f, tbuf[kb + 7][nn] * 128.0f, 1.0f, 3);
            d1 = __builtin_amdgcn_cvt_scalef32_pk_fp4_f32(d1, tbuf[kb + 8][nn] * 128.0f, tbuf[kb + 9][nn] * 128.0f, 1.0f, 0);
            d1 = __builtin_amdgcn_cvt_scalef32_pk_fp4_f32(d1, tbuf[kb + 10][nn] * 128.0f, tbuf[kb + 11][nn] * 128.0f, 1.0f, 1);
            d1 = __builtin_amdgcn_cvt_scalef32_pk_fp4_f32(d1, tbuf[kb + 12][nn] * 128.0f, tbuf[kb + 13][nn] * 128.0f, 1.0f, 2);
            d1 = __builtin_amdgcn_cvt_scalef32_pk_fp4_f32(d1, tbuf[kb + 14][nn] * 128.0f, tbuf[kb + 15][nn] * 128.0f, 1.0f, 3);
            buf.u[0] = d0; buf.u[1] = d1;
#else
            union { unsigned char b[8]; long v; } bb;
#pragma unroll
            for (int bl = 0; bl < 8; bl++) {
                unsigned ob = 0;
#pragma unroll
                for (int i = 0; i < 2; i++) {
                    float v = tbuf[kb + bl * 2 + i][nn] * 128.0f;
                    ob |= f2fp4(v) << (i * 4);
                }
                bb.b[bl] = (unsigned char)ob;
            }
            buf.v = bb.v;
#endif
            *(long*)(dst + (size_t)chunk * 1024 + (q4 * 16 + m16) * 16 + hb * 8) = buf.v;
        }
    } else if (fid < 1456) {
        // dt_w [NL][16][512] -> packed fp8 fragments, K=16 padded to 32; 4 B/thread
        int gid = (fid - 1264) * 256 + threadIdx.x;   // dword index [0, 49152)
        int idx = gid * 4;                            // byte index
        int l = idx >> 14;
        int r14 = idx & 16383;
        int chunk = r14 >> 9;
        int rr = r14 & 511;
        int lane = rr >> 3, byt0 = rr & 7;            // byt0 in {0,4}
        int q = lane >> 4, m16 = lane & 15;
        int col = chunk * 16 + m16;
        float v[4];
#pragma unroll
        for (int j = 0; j < 4; j++) {
            int k = q * 8 + byt0 + j;
            v[j] = (k < DTR) ? dtw[(size_t)l * DTR * DI + (size_t)k * DI + col] : 0.0f;
        }
        *(unsigned*)(dtwP + idx) = pk4fp8(v[0], v[1], v[2], v[3]);
    } else if (fid < 1480) {
        int idx = (fid - 1456) * 256 + threadIdx.x;
        floatx2 v; v.x = cw[(size_t)idx * 4 + 3]; v.y = cb[idx];
        cwcb[idx] = v;
    } else if (fid < 1504) {
        int idx = (fid - 1480) * 256 + threadIdx.x;
        floatx2 v; v.x = db[idx]; v.y = Dv[idx];
        dbdv[idx] = v;
    } else {
        // x [4096 x 230] fp32 -> xpad [4096 x 256] fp8; 4 B/thread
        int gid = (fid - 1504) * 256 + threadIdx.x;   // dword index [0, 262144)
        int r = gid >> 6, c4 = (gid & 63) * 4;
        float v[4];
#pragma unroll
        for (int j = 0; j < 4; j++) {
            int k = c4 + j;
            v[j] = (k < IN_D) ? x[(size_t)r * IN_D + k] : 0.0f;
        }
        *(unsigned*)(xpad + (size_t)gid * 4) = pk4fp8(v[0], v[1], v[2], v[3]);
    }
}

// ---------- the whole network, fused: 256 wgs x 16 rows, 1024 threads ----------
// OPERAND-SWAPPED MFMAs: A = weights (fp4 via cbsz=4 / fp8), B = activations (fp8).
// R7: S2+S3 MERGED. dbl = xc @ x_proj is computed REDUNDANTLY per wave (3 N-tiles
// x 4 kg = 12 scaled MFMAs sharing one set of 8 LDS B-reads — MFMA pipe was 11%,
// redundancy is free). Each thread then holds dt/B/C for its own batch row m16 in
// registers (D-layout row=out-col, col=batch; harness-verified R5/R6):
//   bcv  = sum_j t1[j]*t2[j], + shfl_xor(16) + shfl_xor(32)  (was 8 LDS rd + 3 shfl)
//   bfrag = pk4fp8(t0) redistributed via 2 shfls             (was 8 LDS rd + packs)
// Deletes: the S2->S3 barrier (3 barriers/layer now), the 12-idle-wave S2 phase,
// and the dbls LDS buffer entirely.
// WAR-hazard fix: the gate WRITES y into szs (each thread rewrites only the
// address it alone reads; szs is not an MFMA operand in this stage) so other
// waves' in-flight xcs B-reads are never overwritten. S4 reads szs.
//
// Structure per rounds 0-6: 256 blocks x 16 rows, 1 block/CU, plain
// __launch_bounds__(1024). No min-waves clamp (R1: spills), no 8-row duplication
// (R2: 2x work), single-set layer-top weight hoist (R3 ping-pong spilled; R6 ok).
__global__ __launch_bounds__(1024) void mamba_all(
    const unsigned char* __restrict__ xpad, const unsigned char* __restrict__ WiT,
    const float* __restrict__ bi,
    const unsigned char* __restrict__ ip4, const unsigned char* __restrict__ op4,
    const unsigned char* __restrict__ xp4, const unsigned char* __restrict__ dtwP,
    const floatx2* __restrict__ cwcb, const floatx2* __restrict__ dbdv,
    const float* __restrict__ Wo, const float* __restrict__ bo,
    float* __restrict__ out)
{
    __shared__ unsigned char hs[16 * HB];
    __shared__ unsigned char xcs[16 * XB];
    __shared__ unsigned char szs[16 * XB];

    const int tid = threadIdx.x;
    const int w = tid >> 6, lane = tid & 63;
    const int q = lane >> 4, m16 = lane & 15;
    const int rb = blockIdx.x * 16;
    const long2v z2 = (long2v){0, 0};

    // stage 0: h = xpad @ Wi + bi  (A = Wi fragments, B = batch rows)
    {
        floatx4 a0 = (floatx4){0.f, 0.f, 0.f, 0.f};
        floatx4 a1 = (floatx4){0.f, 0.f, 0.f, 0.f};
        const unsigned char* Bp = xpad + (size_t)(rb + m16) * DM + q * 8;
        const unsigned char* Ap = WiT + (size_t)(w * 4) * 1024 + lane * 16;
#pragma unroll
        for (int g = 0; g < 4; g++) {
            long2v a = *(const long2v*)(Ap + g * 1024);
            long bv0 = *(const long*)(Bp + (g * 2) * 32);
            long bv1 = *(const long*)(Bp + (g * 2 + 1) * 32);
            a0 = __builtin_amdgcn_mfma_f32_16x16x32_fp8_fp8(a.x, bv0, a0, 0, 0, 0);
            a1 = __builtin_amdgcn_mfma_f32_16x16x32_fp8_fp8(a.y, bv1, a1, 0, 0, 0);
        }
        a0 = a0 + a1;
        floatx4 b4 = *(const floatx4*)(bi + w * 16 + q * 4);
        *(unsigned*)(hs + m16 * HB + w * 16 + q * 4) =
            pk4fp8(a0[0] + b4[0], a0[1] + b4[1], a0[2] + b4[2], a0[3] + b4[3]);
    }
    __syncthreads();

    for (int l = 0; l < NL; l++) {
        const unsigned char* ipw = ip4 + (size_t)l * 131072;
        const unsigned char* xpw = xp4 + (size_t)l * 16384;
        const unsigned char* opw = op4 + (size_t)l * 65536;
        const unsigned char* dwp = dtwP + (size_t)l * 16384;
        const floatx2* cc = cwcb + (size_t)l * DI;
        const floatx2* dd = dbdv + (size_t)l * DI;

        // ---- layer-top hoisted weight-fragment loads (one L2 exposure) ----
        long2v a2[12];   // x_proj: 3 N-tiles x 4 kg (chunk = tile*4 + kg)
        {
            const unsigned char* Ap2 = xpw + (size_t)lane * 16;
#pragma unroll
            for (int i = 0; i < 12; i++) a2[i] = *(const long2v*)(Ap2 + (size_t)i * 1024);
        }
        long w3a, w3b;
        {
            const unsigned char* Wp = dwp + (size_t)(w * 2) * 512 + lane * 8;
            w3a = *(const long*)(Wp);
            w3b = *(const long*)(Wp + 512);
        }
        long2v a4[4];
        {
            const unsigned char* Ap4 = opw + (size_t)(w * 4) * 1024 + lane * 16;
#pragma unroll
            for (int i = 0; i < 4; i++) a4[i] = *(const long2v*)(Ap4 + (size_t)i * 1024);
        }

        // stage 1: xz = h @ in_proj  (wave w: cols w*64..+63; K=256 -> 2 kg of 128)
        {
            floatx4 acc[4];
#pragma unroll
            for (int t = 0; t < 4; t++) acc[t] = (floatx4){0.f, 0.f, 0.f, 0.f};
            const unsigned char* Ap = ipw + (size_t)(w * 8) * 1024 + lane * 16;
            const unsigned char* Br = hs + m16 * HB + q * 32;
#pragma unroll
            for (int kg = 0; kg < 2; kg++) {
                union { long2v h[2]; intx8 v; } bv;
                bv.h[0] = *(const long2v*)(Br + kg * 128);
                bv.h[1] = *(const long2v*)(Br + kg * 128 + 16);
#pragma unroll
                for (int t = 0; t < 4; t++) {
                    union { long2v h[2]; intx8 v; } av;
                    av.h[0] = *(const long2v*)(Ap + (size_t)(t * 2 + kg) * 1024);
                    av.h[1] = z2;
                    acc[t] = __builtin_amdgcn_mfma_scale_f32_16x16x128_f8f6f4(
                        av.v, bv.v, acc[t], 4, 0, 0, 120, 0, 127);
                }
            }
            if (w < 8) {
#pragma unroll
                for (int t = 0; t < 4; t++) {
                    int colb = w * 64 + t * 16 + q * 4;
                    floatx4 cA = *(const floatx4*)(cc + colb);
                    floatx4 cB = *(const floatx4*)(cc + colb + 2);
                    float v0 = silu_f(acc[t][0] * cA[0] + cA[1]);
                    float v1 = silu_f(acc[t][1] * cA[2] + cA[3]);
                    float v2 = silu_f(acc[t][2] * cB[0] + cB[1]);
                    float v3 = silu_f(acc[t][3] * cB[2] + cB[3]);
                    *(unsigned*)(xcs + m16 * XB + colb) = pk4fp8(v0, v1, v2, v3);
                }
            } else {
#pragma unroll
                for (int t = 0; t < 4; t++) {
                    int colb = (w - 8) * 64 + t * 16 + q * 4;
                    *(unsigned*)(szs + m16 * XB + colb) =
                        pk4fp8(silu_f(acc[t][0]), silu_f(acc[t][1]),
                               silu_f(acc[t][2]), silu_f(acc[t][3]));
                }
            }
        }
        __syncthreads();

        // ---- merged stage 2+3: per-wave redundant dbl, in-register softmax-free
        //      extraction, dt MFMA, gate. Writes y into szs (WAR-safe). ----
        {
            floatx4 t0 = (floatx4){0.f, 0.f, 0.f, 0.f};   // dt cols q*4..+3, row m16
            floatx4 t1 = (floatx4){0.f, 0.f, 0.f, 0.f};   // B  cols 16+q*4..
            floatx4 t2 = (floatx4){0.f, 0.f, 0.f, 0.f};   // C  cols 32+q*4..
            const unsigned char* Br = xcs + m16 * XB + q * 32;
#pragma unroll
            for (int kg = 0; kg < 4; kg++) {
                union { long2v h[2]; intx8 v; } bv;
                bv.h[0] = *(const long2v*)(Br + kg * 128);
                bv.h[1] = *(const long2v*)(Br + kg * 128 + 16);
                union { long2v h[2]; intx8 v; } av;
                av.h[1] = z2;
                av.h[0] = a2[0 + kg];
                t0 = __builtin_amdgcn_mfma_scale_f32_16x16x128_f8f6f4(
                    av.v, bv.v, t0, 4, 0, 0, 120, 0, 127);
                av.h[0] = a2[4 + kg];
                t1 = __builtin_amdgcn_mfma_scale_f32_16x16x128_f8f6f4(
                    av.v, bv.v, t1, 4, 0, 0, 120, 0, 127);
                av.h[0] = a2[8 + kg];
                t2 = __builtin_amdgcn_mfma_scale_f32_16x16x128_f8f6f4(
                    av.v, bv.v, t2, 4, 0, 0, 120, 0, 127);
            }
            // bcv for own batch row m16: partial over s=q*4..q*4+3, reduce over q
            float p = t1[0] * t2[0] + t1[1] * t2[1] + t1[2] * t2[2] + t1[3] * t2[3];
            p += __shfl_xor(p, 16);
            p += __shfl_xor(p, 32);
            const float bcv = p;

            // bfrag (dt input, col=batch m16, k=q*8..+7): redistribute t0 via shfl
            unsigned dtq = pk4fp8(t0[0], t0[1], t0[2], t0[3]);
            unsigned u0 = __shfl(dtq, q * 32 + m16);        // k = q*8..+3  (thread 2q)
            unsigned u1 = __shfl(dtq, q * 32 + 16 + m16);   // k = q*8+4..+7 (thread 2q+1)
            long bfrag = 0;
            if (q < 2) {
                union { unsigned u[2]; long l; } uv;
                uv.u[0] = u0; uv.u[1] = u1;
                bfrag = uv.l;
            }

            const int cb0 = w * 32 + q * 4;
            floatx4 dA = *(const floatx4*)(dd + cb0);
            floatx4 dB = *(const floatx4*)(dd + cb0 + 2);
            floatx4 dC = *(const floatx4*)(dd + cb0 + 16);
            floatx4 dD = *(const floatx4*)(dd + cb0 + 18);
            floatx4 d0v = (floatx4){dA[0], dA[2], dB[0], dB[2]};   // dt_b
            floatx4 d1v = (floatx4){dC[0], dC[2], dD[0], dD[2]};
            floatx4 Dv0 = (floatx4){dA[1], dA[3], dB[1], dB[3]};   // D
            floatx4 Dv1 = (floatx4){dC[1], dC[3], dD[1], dD[3]};
            d0v = __builtin_amdgcn_mfma_f32_16x16x32_fp8_fp8(w3a, bfrag, d0v, 0, 0, 0);
            d1v = __builtin_amdgcn_mfma_f32_16x16x32_fp8_fp8(w3b, bfrag, d1v, 0, 0, 0);

            const int off = m16 * XB + cb0;
            unsigned xw0 = *(const unsigned*)(xcs + off);
            unsigned zw0 = *(const unsigned*)(szs + off);
            unsigned xw1 = *(const unsigned*)(xcs + off + 16);
            unsigned zw1 = *(const unsigned*)(szs + off + 16);
            float y0[4], y1[4];
            y0[0] = (softplus_f(d0v[0]) * bcv + Dv0[0]) * fp8sel<0>(xw0) * fp8sel<0>(zw0);
            y0[1] = (softplus_f(d0v[1]) * bcv + Dv0[1]) * fp8sel<1>(xw0) * fp8sel<1>(zw0);
            y0[2] = (softplus_f(d0v[2]) * bcv + Dv0[2]) * fp8sel<2>(xw0) * fp8sel<2>(zw0);
            y0[3] = (softplus_f(d0v[3]) * bcv + Dv0[3]) * fp8sel<3>(xw0) * fp8sel<3>(zw0);
            y1[0] = (softplus_f(d1v[0]) * bcv + Dv1[0]) * fp8sel<0>(xw1) * fp8sel<0>(zw1);
            y1[1] = (softplus_f(d1v[1]) * bcv + Dv1[1]) * fp8sel<1>(xw1) * fp8sel<1>(zw1);
            y1[2] = (softplus_f(d1v[2]) * bcv + Dv1[2]) * fp8sel<2>(xw1) * fp8sel<2>(zw1);
            y1[3] = (softplus_f(d1v[3]) * bcv + Dv1[3]) * fp8sel<3>(xw1) * fp8sel<3>(zw1);
            // write y into szs: WAR-safe (each thread rewrites only its own
            // just-read addresses; other waves' MFMAs read only xcs)
            *(unsigned*)(szs + off)      = pk4fp8(y0[0], y0[1], y0[2], y0[3]);
            *(unsigned*)(szs + off + 16) = pk4fp8(y1[0], y1[1], y1[2], y1[3]);
        }
        __syncthreads();

        // stage 4: h = y @ out_proj  (wave w: col-blk w; K=512 -> 4 kg; y in szs)
        {
            floatx4 acc = (floatx4){0.f, 0.f, 0.f, 0.f};
            const unsigned char* Br = szs + m16 * XB + q * 32;
#pragma unroll
            for (int kg = 0; kg < 4; kg++) {
                union { long2v h[2]; intx8 v; } bv;
                bv.h[0] = *(const long2v*)(Br + kg * 128);
                bv.h[1] = *(const long2v*)(Br + kg * 128 + 16);
                union { long2v h[2]; intx8 v; } av;
                av.h[0] = a4[kg];
                av.h[1] = z2;
                acc = __builtin_amdgcn_mfma_scale_f32_16x16x128_f8f6f4(
                    av.v, bv.v, acc, 4, 0, 0, 120, 0, 127);
            }
            *(unsigned*)(hs + m16 * HB + w * 16 + q * 4) =
                pk4fp8(acc[0], acc[1], acc[2], acc[3]);
        }
        __syncthreads();
    }

    // final: wave w reduces row w
    {
        unsigned hw = *(const unsigned*)(hs + w * HB + lane * 4);
        floatx4 w4 = *(const floatx4*)(Wo + lane * 4);
        float s = fp8sel<0>(hw) * w4[0] + fp8sel<1>(hw) * w4[1]
                + fp8sel<2>(hw) * w4[2] + fp8sel<3>(hw) * w4[3];
#pragma unroll
        for (int off = 32; off > 0; off >>= 1) s += __shfl_down(s, off);
        if (lane == 0) out[rb + w] = s + bo[0];
    }
}

extern "C" void kernel_launch(void* const* d_in, const int* in_sizes, int n_in,
                              void* d_out, int out_size, void* d_ws, size_t ws_size,
                              hipStream_t stream)
{
    const float* x       = (const float*)d_in[0];
    const float* Wi      = (const float*)d_in[1];
    const float* bi      = (const float*)d_in[2];
    const float* in_proj = (const float*)d_in[3];
    const float* conv_w  = (const float*)d_in[4];
    const float* conv_b  = (const float*)d_in[5];
    const float* x_proj  = (const float*)d_in[6];
    const float* dt_w    = (const float*)d_in[7];
    const float* dt_b    = (const float*)d_in[8];
    // d_in[9] = A_log: dead (L==1, h0==0)
    const float* Dp      = (const float*)d_in[10];
    const float* out_pw  = (const float*)d_in[11];
    const float* Wo      = (const float*)d_in[12];
    const float* bo      = (const float*)d_in[13];

    unsigned char* ws = (unsigned char*)d_ws;
    unsigned char* xpad = ws;                              // 1 MB
    unsigned char* WiT  = xpad + (size_t)NB * DM;          // 64 KB fp8
    unsigned char* dtwP = WiT + (size_t)DM * DM;           // 12*16 KB fp8
    floatx2* cwcb = (floatx2*)(dtwP + (size_t)NL * 16384); // 12*512 float2
    floatx2* dbdv = cwcb + (size_t)NL * DI;                // 12*512 float2
    unsigned char* ip4 = (unsigned char*)(dbdv + (size_t)NL * DI); // 12*128 KB fp4
    unsigned char* op4 = ip4 + (size_t)NL * 131072;        // 12*64 KB fp4
    unsigned char* xp4 = op4 + (size_t)NL * 65536;         // 12*16 KB fp4

    pack_all<<<dim3(2528), dim3(256), 0, stream>>>(
        x, Wi, in_proj, out_pw, x_proj, dt_w, conv_w, conv_b, dt_b, Dp,
        xpad, WiT, dtwP, ip4, op4, xp4, cwcb, dbdv);

    mamba_all<<<dim3(NB / 16), dim3(1024), 0, stream>>>(
        xpad, WiT, bi, ip4, op4, xp4, dtwP,
        cwcb, dbdv, Wo, bo, (float*)d_out);
}

// Round 8
// 177.153 us; speedup vs baseline: 1.0012x; 1.0012x over previous
//
#include <hip/hip_runtime.h>
#include <hip/hip_fp8.h>
#include <math.h>

#define NB 4096
#define IN_D 230
#define DM 256
#define NL 12
#define DST 16
#define DI 512
#define DTR 16
#define XPN 48
#define XB 528    // xcs/szs row stride (bytes), 16-B aligned
#define HB 272    // hs row stride (bytes), 16-B aligned

typedef __attribute__((ext_vector_type(4))) float floatx4;
typedef __attribute__((ext_vector_type(2))) float floatx2;
typedef __attribute__((ext_vector_type(2))) long long2v;
typedef __attribute__((ext_vector_type(4))) int intx4;
typedef __attribute__((ext_vector_type(8))) int intx8;

__device__ __forceinline__ float silu_f(float x) {
    return x * __builtin_amdgcn_rcpf(1.0f + __expf(-x));
}
__device__ __forceinline__ float softplus_f(float x) {
    return (x > 20.0f) ? x : __logf(1.0f + __expf(x));
}

__device__ __forceinline__ unsigned char f2fp8(float x) {
#if __has_builtin(__builtin_amdgcn_cvt_pk_fp8_f32)
    return (unsigned char)(__builtin_amdgcn_cvt_pk_fp8_f32(x, x, 0, false) & 0xff);
#else
    __hip_fp8_e4m3 t(x); return (unsigned char)t.__x;
#endif
}
// pack 4 floats -> 4 fp8 bytes in one dword
__device__ __forceinline__ unsigned pk4fp8(float a, float b, float c, float d) {
    unsigned w = __builtin_amdgcn_cvt_pk_fp8_f32(a, b, 0, false);
    return __builtin_amdgcn_cvt_pk_fp8_f32(c, d, w, true);
}
// decode byte S of dword w as fp8 — S must be a literal-constant selector
template<int S>
__device__ __forceinline__ float fp8sel(unsigned w) {
    return __builtin_amdgcn_cvt_f32_fp8((int)w, S);
}

// e2m1 encode, round-to-nearest (fallback only — HW cvt used when available)
__device__ __forceinline__ unsigned f2fp4(float x) {
    float ax = fabsf(x);
    unsigned s = (x < 0.0f) ? 8u : 0u;
    unsigned m;
    if      (ax < 0.25f) m = 0;
    else if (ax < 0.75f) m = 1;
    else if (ax < 1.25f) m = 2;
    else if (ax < 1.75f) m = 3;
    else if (ax < 2.50f) m = 4;
    else if (ax < 3.50f) m = 5;
    else if (ax < 5.00f) m = 6;
    else                 m = 7;
    return s | m;
}

// ---------- single prep kernel: packs everything + converts x ----------
// Block ranges:
// [0,16)       Wi  -> fp8 fragment chunks (stage 0)
// [16,784)     in_proj  -> fp4 (12 x 64 tiles)
// [784,1168)   out_proj -> fp4 (12 x 32 tiles)
// [1168,1264)  x_proj   -> fp4 (12 x 8 tiles)
// [1264,1456)  dt_w -> fp8 fragments (K=16 pad 32), 4 B/thread packed
// [1456,1480)  cwcb table | [1480,1504) dbdv table
// [1504,2528)  x -> xpad fp8, 4 B/thread packed
__global__ __launch_bounds__(256) void pack_all(
    const float* __restrict__ x,
    const float* __restrict__ Wi, const float* __restrict__ ip,
    const float* __restrict__ op, const float* __restrict__ xp,
    const float* __restrict__ dtw,
    const float* __restrict__ cw, const float* __restrict__ cb,
    const float* __restrict__ db, const float* __restrict__ Dv,
    unsigned char* __restrict__ xpad,
    unsigned char* __restrict__ WiT, unsigned char* __restrict__ dtwP,
    unsigned char* __restrict__ ip4, unsigned char* __restrict__ op4,
    unsigned char* __restrict__ xp4,
    floatx2* __restrict__ cwcb, floatx2* __restrict__ dbdv)
{
    __shared__ float tbuf[64][68];
    const int fid = blockIdx.x;

    if (fid < 1264) {
        const float* src; unsigned char* dst;
        int K, N, ngK, t;
        bool isfp4;
        if (fid < 16) {
            src = Wi; dst = WiT; K = IN_D; N = DM; ngK = 4; t = fid; isfp4 = false;
        } else if (fid < 784) {
            int local = fid - 16; int l = local >> 6; t = local & 63;
            K = DM; N = 2 * DI; ngK = 4; isfp4 = true;
            src = ip + (size_t)l * K * N; dst = ip4 + (size_t)l * 131072;
        } else if (fid < 1168) {
            int local = fid - 784; int l = local >> 5; t = local & 31;
            K = DI; N = DM; ngK = 8; isfp4 = true;
            src = op + (size_t)l * K * N; dst = op4 + (size_t)l * 65536;
        } else {
            int local = fid - 1168; int l = local >> 3; t = local & 7;
            K = DI; N = XPN; ngK = 8; isfp4 = true;
            src = xp + (size_t)l * K * N; dst = xp4 + (size_t)l * 16384;
        }
        const int g = t % ngK, nb = t / ngK;
        const int k0 = g * 64, n0 = nb * 64;
        {
            const int t4 = threadIdx.x;
#pragma unroll
            for (int i = 0; i < 4; i++) {
                int fi = i * 256 + t4;           // float4 index in tile (0..1023)
                int lr = fi >> 4;                // local row 0..63
                int lc = (fi & 15) * 4;          // local col 0,4,..60
                int kk = k0 + lr, nn = n0 + lc;
                floatx4 v;
                if (kk < K && nn + 3 < N) {
                    v = *(const floatx4*)(src + (size_t)kk * N + nn);
                } else {
#pragma unroll
                    for (int j = 0; j < 4; j++)
                        v[j] = (kk < K && nn + j < N) ? src[(size_t)kk * N + nn + j] : 0.0f;
                }
                *(floatx4*)(&tbuf[lr][lc]) = v;
            }
        }
        __syncthreads();
        if (!isfp4) {
            // fp8 fragment chunk (16 cols x 64 k -> 1024 B)
            const int cbi = threadIdx.x >> 6;
            const int lane = threadIdx.x & 63;
            const int q = lane >> 4, m16 = lane & 15;
            const int chunk = (nb * 4 + cbi) * ngK + g;
            union { unsigned char b[16]; intx4 v; } buf;
#pragma unroll
            for (int sub = 0; sub < 2; sub++)
#pragma unroll
                for (int byt = 0; byt < 8; byt++) {
                    int k = sub * 32 + q * 8 + byt;
                    int n = cbi * 16 + m16;
                    buf.b[sub * 8 + byt] = f2fp8(tbuf[k][n]);
                }
            *(intx4*)(dst + (size_t)chunk * 1024 + lane * 16) = buf.v;
        } else {
            // fp4 fragment half-chunk: tile = k-group g (64 wide) of fp4 chunk kg=g>>1
            const int kg = g >> 1, half = g & 1;
            const int nkg128 = ngK >> 1;
            const int cbi = threadIdx.x >> 6;          // 0..3
            const int rem = threadIdx.x & 63;
            const int q4loc = rem >> 5;                // 0..1
            const int hb = (rem >> 4) & 1;             // 0..1
            const int m16 = rem & 15;
            const int q4 = half * 2 + q4loc;
            const int chunk = (nb * 4 + cbi) * nkg128 + kg;
            const int kb = q4loc * 32 + hb * 16;
            const int nn = cbi * 16 + m16;
            union { unsigned u[2]; long v; } buf;
#if __has_builtin(__builtin_amdgcn_cvt_scalef32_pk_fp4_f32)
            unsigned d0 = 0, d1 = 0;
            d0 = __builtin_amdgcn_cvt_scalef32_pk_fp4_f32(d0, tbuf[kb + 0][nn] * 128.0f, tbuf[kb + 1][nn] * 128.0f, 1.0f, 0);
            d0 = __builtin_amdgcn_cvt_scalef32_pk_fp4_f32(d0, tbuf[kb + 2][nn] * 128.0f, tbuf[kb + 3][nn] * 128.0f, 1.0f, 1);
            d0 = __builtin_amdgcn_cvt_scalef32_pk_fp4_f32(d0, tbuf[kb + 4][nn] * 128.0f, tbuf[kb + 5][nn] * 128.0f, 1.0f, 2);
            d0 = __builtin_amdgcn_cvt_scalef32_pk_fp4_f32(d0, tbuf[kb + 6][nn] * 128.0f, tbuf[kb + 7][nn] * 128.0f, 1.0f, 3);
            d1 = __builtin_amdgcn_cvt_scalef32_pk_fp4_f32(d1, tbuf[kb + 8][nn] * 128.0f, tbuf[kb + 9][nn] * 128.0f, 1.0f, 0);
            d1 = __builtin_amdgcn_cvt_scalef32_pk_fp4_f32(d1, tbuf[kb + 10][nn] * 128.0f, tbuf[kb + 11][nn] * 128.0f, 1.0f, 1);
            d1 = __builtin_amdgcn_cvt_scalef32_pk_fp4_f32(d1, tbuf[kb + 12][nn] * 128.0f, tbuf[kb + 13][nn] * 128.0f, 1.0f, 2);
            d1 = __builtin_amdgcn_cvt_scalef32_pk_fp4_f32(d1, tbuf[kb + 14][nn] * 128.0f, tbuf[kb + 15][nn] * 128.0f, 1.0f, 3);
            buf.u[0] = d0; buf.u[1] = d1;
#else
            union { unsigned char b[8]; long v; } bb;
#pragma unroll
            for (int bl = 0; bl < 8; bl++) {
                unsigned ob = 0;
#pragma unroll
                for (int i = 0; i < 2; i++) {
                    float v = tbuf[kb + bl * 2 + i][nn] * 128.0f;
                    ob |= f2fp4(v) << (i * 4);
                }
                bb.b[bl] = (unsigned char)ob;
            }
            buf.v = bb.v;
#endif
            *(long*)(dst + (size_t)chunk * 1024 + (q4 * 16 + m16) * 16 + hb * 8) = buf.v;
        }
    } else if (fid < 1456) {
        // dt_w [NL][16][512] -> packed fp8 fragments, K=16 padded to 32; 4 B/thread
        int gid = (fid - 1264) * 256 + threadIdx.x;   // dword index [0, 49152)
        int idx = gid * 4;                            // byte index
        int l = idx >> 14;
        int r14 = idx & 16383;
        int chunk = r14 >> 9;
        int rr = r14 & 511;
        int lane = rr >> 3, byt0 = rr & 7;            // byt0 in {0,4}
        int q = lane >> 4, m16 = lane & 15;
        int col = chunk * 16 + m16;
        float v[4];
#pragma unroll
        for (int j = 0; j < 4; j++) {
            int k = q * 8 + byt0 + j;
            v[j] = (k < DTR) ? dtw[(size_t)l * DTR * DI + (size_t)k * DI + col] : 0.0f;
        }
        *(unsigned*)(dtwP + idx) = pk4fp8(v[0], v[1], v[2], v[3]);
    } else if (fid < 1480) {
        int idx = (fid - 1456) * 256 + threadIdx.x;
        floatx2 v; v.x = cw[(size_t)idx * 4 + 3]; v.y = cb[idx];
        cwcb[idx] = v;
    } else if (fid < 1504) {
        int idx = (fid - 1480) * 256 + threadIdx.x;
        floatx2 v; v.x = db[idx]; v.y = Dv[idx];
        dbdv[idx] = v;
    } else {
        // x [4096 x 230] fp32 -> xpad [4096 x 256] fp8; 4 B/thread
        int gid = (fid - 1504) * 256 + threadIdx.x;   // dword index [0, 262144)
        int r = gid >> 6, c4 = (gid & 63) * 4;
        float v[4];
#pragma unroll
        for (int j = 0; j < 4; j++) {
            int k = c4 + j;
            v[j] = (k < IN_D) ? x[(size_t)r * IN_D + k] : 0.0f;
        }
        *(unsigned*)(xpad + (size_t)gid * 4) = pk4fp8(v[0], v[1], v[2], v[3]);
    }
}

// ---------- the whole network, fused: 256 wgs x 16 rows, 1024 threads ----------
// OPERAND-SWAPPED MFMAs: A = weights (fp4 via cbsz=4 / fp8), B = activations (fp8).
// R8 = R7's merged S2+S3 minus the register poison. R7 evidence: for 1024-thread
// MFMA kernels the allocator holds arch-VGPRs at a hard 64 (unified file splits
// 128/wave-budget into 64V+64A); R7's a2[12] hoist (+24 live-across-stages regs)
// overflowed to scratch (WRITE_SIZE 16KB -> 2MB) and regressed 77.6 -> 89.3us.
// Fix: x_proj fragments are loaded INSIDE the merged stage, software-pipelined
// (3 frags for kg+1 issued before kg's 3 MFMAs; peak 6 frags = 12 transient
// VGPRs reusing S1's dead acc registers). w3/a4 hoists stay (R6-proven, no spill).
// Merged stage (from R7, logic verified absmax 0.0):
//   - dbl computed redundantly per wave (12 scaled MFMAs sharing 8 LDS B-reads)
//   - bcv via 4 FMA + 2 shfl_xor; bfrag via pk4fp8 + 2 shfls (no dbls LDS buffer)
//   - gate writes y into szs (WAR-safe vs other waves' xcs MFMA reads); S4 reads szs
//   - 3 barriers/layer (was 4)
__global__ __launch_bounds__(1024) void mamba_all(
    const unsigned char* __restrict__ xpad, const unsigned char* __restrict__ WiT,
    const float* __restrict__ bi,
    const unsigned char* __restrict__ ip4, const unsigned char* __restrict__ op4,
    const unsigned char* __restrict__ xp4, const unsigned char* __restrict__ dtwP,
    const floatx2* __restrict__ cwcb, const floatx2* __restrict__ dbdv,
    const float* __restrict__ Wo, const float* __restrict__ bo,
    float* __restrict__ out)
{
    __shared__ unsigned char hs[16 * HB];
    __shared__ unsigned char xcs[16 * XB];
    __shared__ unsigned char szs[16 * XB];

    const int tid = threadIdx.x;
    const int w = tid >> 6, lane = tid & 63;
    const int q = lane >> 4, m16 = lane & 15;
    const int rb = blockIdx.x * 16;
    const long2v z2 = (long2v){0, 0};

    // stage 0: h = xpad @ Wi + bi  (A = Wi fragments, B = batch rows)
    {
        floatx4 a0 = (floatx4){0.f, 0.f, 0.f, 0.f};
        floatx4 a1 = (floatx4){0.f, 0.f, 0.f, 0.f};
        const unsigned char* Bp = xpad + (size_t)(rb + m16) * DM + q * 8;
        const unsigned char* Ap = WiT + (size_t)(w * 4) * 1024 + lane * 16;
#pragma unroll
        for (int g = 0; g < 4; g++) {
            long2v a = *(const long2v*)(Ap + g * 1024);
            long bv0 = *(const long*)(Bp + (g * 2) * 32);
            long bv1 = *(const long*)(Bp + (g * 2 + 1) * 32);
            a0 = __builtin_amdgcn_mfma_f32_16x16x32_fp8_fp8(a.x, bv0, a0, 0, 0, 0);
            a1 = __builtin_amdgcn_mfma_f32_16x16x32_fp8_fp8(a.y, bv1, a1, 0, 0, 0);
        }
        a0 = a0 + a1;
        floatx4 b4 = *(const floatx4*)(bi + w * 16 + q * 4);
        *(unsigned*)(hs + m16 * HB + w * 16 + q * 4) =
            pk4fp8(a0[0] + b4[0], a0[1] + b4[1], a0[2] + b4[2], a0[3] + b4[3]);
    }
    __syncthreads();

    for (int l = 0; l < NL; l++) {
        const unsigned char* ipw = ip4 + (size_t)l * 131072;
        const unsigned char* xpw = xp4 + (size_t)l * 16384;
        const unsigned char* opw = op4 + (size_t)l * 65536;
        const unsigned char* dwp = dtwP + (size_t)l * 16384;
        const floatx2* cc = cwcb + (size_t)l * DI;
        const floatx2* dd = dbdv + (size_t)l * DI;

        // ---- layer-top hoisted weight-fragment loads (R6-proven set only) ----
        long w3a, w3b;
        {
            const unsigned char* Wp = dwp + (size_t)(w * 2) * 512 + lane * 8;
            w3a = *(const long*)(Wp);
            w3b = *(const long*)(Wp + 512);
        }
        long2v a4[4];
        {
            const unsigned char* Ap4 = opw + (size_t)(w * 4) * 1024 + lane * 16;
#pragma unroll
            for (int i = 0; i < 4; i++) a4[i] = *(const long2v*)(Ap4 + (size_t)i * 1024);
        }

        // stage 1: xz = h @ in_proj  (wave w: cols w*64..+63; K=256 -> 2 kg of 128)
        {
            floatx4 acc[4];
#pragma unroll
            for (int t = 0; t < 4; t++) acc[t] = (floatx4){0.f, 0.f, 0.f, 0.f};
            const unsigned char* Ap = ipw + (size_t)(w * 8) * 1024 + lane * 16;
            const unsigned char* Br = hs + m16 * HB + q * 32;
#pragma unroll
            for (int kg = 0; kg < 2; kg++) {
                union { long2v h[2]; intx8 v; } bv;
                bv.h[0] = *(const long2v*)(Br + kg * 128);
                bv.h[1] = *(const long2v*)(Br + kg * 128 + 16);
#pragma unroll
                for (int t = 0; t < 4; t++) {
                    union { long2v h[2]; intx8 v; } av;
                    av.h[0] = *(const long2v*)(Ap + (size_t)(t * 2 + kg) * 1024);
                    av.h[1] = z2;
                    acc[t] = __builtin_amdgcn_mfma_scale_f32_16x16x128_f8f6f4(
                        av.v, bv.v, acc[t], 4, 0, 0, 120, 0, 127);
                }
            }
            if (w < 8) {
#pragma unroll
                for (int t = 0; t < 4; t++) {
                    int colb = w * 64 + t * 16 + q * 4;
                    floatx4 cA = *(const floatx4*)(cc + colb);
                    floatx4 cB = *(const floatx4*)(cc + colb + 2);
                    float v0 = silu_f(acc[t][0] * cA[0] + cA[1]);
                    float v1 = silu_f(acc[t][1] * cA[2] + cA[3]);
                    float v2 = silu_f(acc[t][2] * cB[0] + cB[1]);
                    float v3 = silu_f(acc[t][3] * cB[2] + cB[3]);
                    *(unsigned*)(xcs + m16 * XB + colb) = pk4fp8(v0, v1, v2, v3);
                }
            } else {
#pragma unroll
                for (int t = 0; t < 4; t++) {
                    int colb = (w - 8) * 64 + t * 16 + q * 4;
                    *(unsigned*)(szs + m16 * XB + colb) =
                        pk4fp8(silu_f(acc[t][0]), silu_f(acc[t][1]),
                               silu_f(acc[t][2]), silu_f(acc[t][3]));
                }
            }
        }
        __syncthreads();

        // ---- merged stage 2+3: in-stage pipelined x_proj loads, per-wave
        //      redundant dbl, in-register extraction, dt MFMA, gate -> szs ----
        {
            const unsigned char* Ap2 = xpw + (size_t)lane * 16;
            // prefetch kg=0's three fragments (tile t at offset (t*4+kg)*1024)
            long2v f0 = *(const long2v*)(Ap2);
            long2v f1 = *(const long2v*)(Ap2 + 4096);
            long2v f2 = *(const long2v*)(Ap2 + 8192);

            floatx4 t0 = (floatx4){0.f, 0.f, 0.f, 0.f};   // dt cols q*4..+3, row m16
            floatx4 t1 = (floatx4){0.f, 0.f, 0.f, 0.f};   // B  cols 16+q*4..
            floatx4 t2 = (floatx4){0.f, 0.f, 0.f, 0.f};   // C  cols 32+q*4..
            const unsigned char* Br = xcs + m16 * XB + q * 32;
#pragma unroll
            for (int kg = 0; kg < 4; kg++) {
                union { long2v h[2]; intx8 v; } bv;
                bv.h[0] = *(const long2v*)(Br + kg * 128);
                bv.h[1] = *(const long2v*)(Br + kg * 128 + 16);
                long2v n0, n1, n2;
                if (kg < 3) {
                    n0 = *(const long2v*)(Ap2 + (size_t)(kg + 1) * 1024);
                    n1 = *(const long2v*)(Ap2 + (size_t)(kg + 5) * 1024);
                    n2 = *(const long2v*)(Ap2 + (size_t)(kg + 9) * 1024);
                }
                union { long2v h[2]; intx8 v; } av;
                av.h[1] = z2;
                av.h[0] = f0;
                t0 = __builtin_amdgcn_mfma_scale_f32_16x16x128_f8f6f4(
                    av.v, bv.v, t0, 4, 0, 0, 120, 0, 127);
                av.h[0] = f1;
                t1 = __builtin_amdgcn_mfma_scale_f32_16x16x128_f8f6f4(
                    av.v, bv.v, t1, 4, 0, 0, 120, 0, 127);
                av.h[0] = f2;
                t2 = __builtin_amdgcn_mfma_scale_f32_16x16x128_f8f6f4(
                    av.v, bv.v, t2, 4, 0, 0, 120, 0, 127);
                if (kg < 3) { f0 = n0; f1 = n1; f2 = n2; }
            }
            // bcv for own batch row m16: partial over s=q*4..q*4+3, reduce over q
            float p = t1[0] * t2[0] + t1[1] * t2[1] + t1[2] * t2[2] + t1[3] * t2[3];
            p += __shfl_xor(p, 16);
            p += __shfl_xor(p, 32);
            const float bcv = p;

            // bfrag (dt input, col=batch m16, k=q*8..+7): redistribute t0 via shfl
            unsigned dtq = pk4fp8(t0[0], t0[1], t0[2], t0[3]);
            unsigned u0 = __shfl(dtq, q * 32 + m16);        // k = q*8..+3
            unsigned u1 = __shfl(dtq, q * 32 + 16 + m16);   // k = q*8+4..+7
            long bfrag = 0;
            if (q < 2) {
                union { unsigned u[2]; long l; } uv;
                uv.u[0] = u0; uv.u[1] = u1;
                bfrag = uv.l;
            }

            const int cb0 = w * 32 + q * 4;
            floatx4 dA = *(const floatx4*)(dd + cb0);
            floatx4 dB = *(const floatx4*)(dd + cb0 + 2);
            floatx4 dC = *(const floatx4*)(dd + cb0 + 16);
            floatx4 dD = *(const floatx4*)(dd + cb0 + 18);
            floatx4 d0v = (floatx4){dA[0], dA[2], dB[0], dB[2]};   // dt_b
            floatx4 d1v = (floatx4){dC[0], dC[2], dD[0], dD[2]};
            floatx4 Dv0 = (floatx4){dA[1], dA[3], dB[1], dB[3]};   // D
            floatx4 Dv1 = (floatx4){dC[1], dC[3], dD[1], dD[3]};
            d0v = __builtin_amdgcn_mfma_f32_16x16x32_fp8_fp8(w3a, bfrag, d0v, 0, 0, 0);
            d1v = __builtin_amdgcn_mfma_f32_16x16x32_fp8_fp8(w3b, bfrag, d1v, 0, 0, 0);

            const int off = m16 * XB + cb0;
            unsigned xw0 = *(const unsigned*)(xcs + off);
            unsigned zw0 = *(const unsigned*)(szs + off);
            unsigned xw1 = *(const unsigned*)(xcs + off + 16);
            unsigned zw1 = *(const unsigned*)(szs + off + 16);
            float y0[4], y1[4];
            y0[0] = (softplus_f(d0v[0]) * bcv + Dv0[0]) * fp8sel<0>(xw0) * fp8sel<0>(zw0);
            y0[1] = (softplus_f(d0v[1]) * bcv + Dv0[1]) * fp8sel<1>(xw0) * fp8sel<1>(zw0);
            y0[2] = (softplus_f(d0v[2]) * bcv + Dv0[2]) * fp8sel<2>(xw0) * fp8sel<2>(zw0);
            y0[3] = (softplus_f(d0v[3]) * bcv + Dv0[3]) * fp8sel<3>(xw0) * fp8sel<3>(zw0);
            y1[0] = (softplus_f(d1v[0]) * bcv + Dv1[0]) * fp8sel<0>(xw1) * fp8sel<0>(zw1);
            y1[1] = (softplus_f(d1v[1]) * bcv + Dv1[1]) * fp8sel<1>(xw1) * fp8sel<1>(zw1);
            y1[2] = (softplus_f(d1v[2]) * bcv + Dv1[2]) * fp8sel<2>(xw1) * fp8sel<2>(zw1);
            y1[3] = (softplus_f(d1v[3]) * bcv + Dv1[3]) * fp8sel<3>(xw1) * fp8sel<3>(zw1);
            // write y into szs: WAR-safe (each thread rewrites only its own
            // just-read addresses; other waves' MFMAs read only xcs)
            *(unsigned*)(szs + off)      = pk4fp8(y0[0], y0[1], y0[2], y0[3]);
            *(unsigned*)(szs + off + 16) = pk4fp8(y1[0], y1[1], y1[2], y1[3]);
        }
        __syncthreads();

        // stage 4: h = y @ out_proj  (wave w: col-blk w; K=512 -> 4 kg; y in szs)
        {
            floatx4 acc = (floatx4){0.f, 0.f, 0.f, 0.f};
            const unsigned char* Br = szs + m16 * XB + q * 32;
#pragma unroll
            for (int kg = 0; kg < 4; kg++) {
                union { long2v h[2]; intx8 v; } bv;
                bv.h[0] = *(const long2v*)(Br + kg * 128);
                bv.h[1] = *(const long2v*)(Br + kg * 128 + 16);
                union { long2v h[2]; intx8 v; } av;
                av.h[0] = a4[kg];
                av.h[1] = z2;
                acc = __builtin_amdgcn_mfma_scale_f32_16x16x128_f8f6f4(
                    av.v, bv.v, acc, 4, 0, 0, 120, 0, 127);
            }
            *(unsigned*)(hs + m16 * HB + w * 16 + q * 4) =
                pk4fp8(acc[0], acc[1], acc[2], acc[3]);
        }
        __syncthreads();
    }

    // final: wave w reduces row w
    {
        unsigned hw = *(const unsigned*)(hs + w * HB + lane * 4);
        floatx4 w4 = *(const floatx4*)(Wo + lane * 4);
        float s = fp8sel<0>(hw) * w4[0] + fp8sel<1>(hw) * w4[1]
                + fp8sel<2>(hw) * w4[2] + fp8sel<3>(hw) * w4[3];
#pragma unroll
        for (int off = 32; off > 0; off >>= 1) s += __shfl_down(s, off);
        if (lane == 0) out[rb + w] = s + bo[0];
    }
}

extern "C" void kernel_launch(void* const* d_in, const int* in_sizes, int n_in,
                              void* d_out, int out_size, void* d_ws, size_t ws_size,
                              hipStream_t stream)
{
    const float* x       = (const float*)d_in[0];
    const float* Wi      = (const float*)d_in[1];
    const float* bi      = (const float*)d_in[2];
    const float* in_proj = (const float*)d_in[3];
    const float* conv_w  = (const float*)d_in[4];
    const float* conv_b  = (const float*)d_in[5];
    const float* x_proj  = (const float*)d_in[6];
    const float* dt_w    = (const float*)d_in[7];
    const float* dt_b    = (const float*)d_in[8];
    // d_in[9] = A_log: dead (L==1, h0==0)
    const float* Dp      = (const float*)d_in[10];
    const float* out_pw  = (const float*)d_in[11];
    const float* Wo      = (const float*)d_in[12];
    const float* bo      = (const float*)d_in[13];

    unsigned char* ws = (unsigned char*)d_ws;
    unsigned char* xpad = ws;                              // 1 MB
    unsigned char* WiT  = xpad + (size_t)NB * DM;          // 64 KB fp8
    unsigned char* dtwP = WiT + (size_t)DM * DM;           // 12*16 KB fp8
    floatx2* cwcb = (floatx2*)(dtwP + (size_t)NL * 16384); // 12*512 float2
    floatx2* dbdv = cwcb + (size_t)NL * DI;                // 12*512 float2
    unsigned char* ip4 = (unsigned char*)(dbdv + (size_t)NL * DI); // 12*128 KB fp4
    unsigned char* op4 = ip4 + (size_t)NL * 131072;        // 12*64 KB fp4
    unsigned char* xp4 = op4 + (size_t)NL * 65536;         // 12*16 KB fp4

    pack_all<<<dim3(2528), dim3(256), 0, stream>>>(
        x, Wi, in_proj, out_pw, x_proj, dt_w, conv_w, conv_b, dt_b, Dp,
        xpad, WiT, dtwP, ip4, op4, xp4, cwcb, dbdv);

    mamba_all<<<dim3(NB / 16), dim3(1024), 0, stream>>>(
        xpad, WiT, bi, ip4, op4, xp4, dtwP,
        cwcb, dbdv, Wo, bo, (float*)d_out);
}

// Round 9
// 165.531 us; speedup vs baseline: 1.0715x; 1.0702x over previous
//
#include <hip/hip_runtime.h>
#include <hip/hip_fp8.h>
#include <math.h>

#define NB 4096
#define IN_D 230
#define DM 256
#define NL 12
#define DST 16
#define DI 512
#define DTR 16
#define XPN 48
#define XB 528    // xcs/szs row stride (bytes), 16-B aligned
#define HB 272    // hs row stride (bytes), 16-B aligned

typedef __attribute__((ext_vector_type(4))) float floatx4;
typedef __attribute__((ext_vector_type(2))) float floatx2;
typedef __attribute__((ext_vector_type(2))) long long2v;
typedef __attribute__((ext_vector_type(4))) int intx4;
typedef __attribute__((ext_vector_type(8))) int intx8;

__device__ __forceinline__ float silu_f(float x) {
    return x * __builtin_amdgcn_rcpf(1.0f + __expf(-x));
}
__device__ __forceinline__ float softplus_f(float x) {
    return (x > 20.0f) ? x : __logf(1.0f + __expf(x));
}

__device__ __forceinline__ unsigned char f2fp8(float x) {
#if __has_builtin(__builtin_amdgcn_cvt_pk_fp8_f32)
    return (unsigned char)(__builtin_amdgcn_cvt_pk_fp8_f32(x, x, 0, false) & 0xff);
#else
    __hip_fp8_e4m3 t(x); return (unsigned char)t.__x;
#endif
}
// pack 4 floats -> 4 fp8 bytes in one dword
__device__ __forceinline__ unsigned pk4fp8(float a, float b, float c, float d) {
    unsigned w = __builtin_amdgcn_cvt_pk_fp8_f32(a, b, 0, false);
    return __builtin_amdgcn_cvt_pk_fp8_f32(c, d, w, true);
}
// decode byte S of dword w as fp8 — S must be a literal-constant selector
template<int S>
__device__ __forceinline__ float fp8sel(unsigned w) {
    return __builtin_amdgcn_cvt_f32_fp8((int)w, S);
}
// decode all 4 fp8 bytes of dword w into f32[4] — packed (2 instrs) when available
__device__ __forceinline__ void up4fp8(unsigned w, float* o) {
#if __has_builtin(__builtin_amdgcn_cvt_pk_f32_fp8)
    floatx2 lo = __builtin_amdgcn_cvt_pk_f32_fp8((int)w, false);
    floatx2 hi = __builtin_amdgcn_cvt_pk_f32_fp8((int)w, true);
    o[0] = lo.x; o[1] = lo.y; o[2] = hi.x; o[3] = hi.y;
#else
    o[0] = fp8sel<0>(w); o[1] = fp8sel<1>(w); o[2] = fp8sel<2>(w); o[3] = fp8sel<3>(w);
#endif
}

// e2m1 encode, round-to-nearest (fallback only — HW cvt used when available)
__device__ __forceinline__ unsigned f2fp4(float x) {
    float ax = fabsf(x);
    unsigned s = (x < 0.0f) ? 8u : 0u;
    unsigned m;
    if      (ax < 0.25f) m = 0;
    else if (ax < 0.75f) m = 1;
    else if (ax < 1.25f) m = 2;
    else if (ax < 1.75f) m = 3;
    else if (ax < 2.50f) m = 4;
    else if (ax < 3.50f) m = 5;
    else if (ax < 5.00f) m = 6;
    else                 m = 7;
    return s | m;
}

// ---------- single prep kernel: packs everything + converts x ----------
// Block ranges:
// [0,16)       Wi  -> fp8 fragment chunks (stage 0)
// [16,784)     in_proj  -> fp4 (12 x 64 tiles)
// [784,1168)   out_proj -> fp4 (12 x 32 tiles)
// [1168,1264)  x_proj   -> fp4 (12 x 8 tiles)
// [1264,1456)  dt_w -> fp8 fragments (K=16 pad 32), 4 B/thread packed
// [1456,1480)  cwcb table | [1480,1504) dbdv table
// [1504,2528)  x -> xpad fp8, 4 B/thread packed
// NOTE (R8 post-mortem): pack_all compute is ~3us (205M VALU ops / 32k lanes);
// the persistent ~86-95us total-minus-mamba gap is fixed harness/dispatch
// overhead, invariant under grid x2.4 and SW->HW encode changes. Don't optimize
// this kernel further.
__global__ __launch_bounds__(256) void pack_all(
    const float* __restrict__ x,
    const float* __restrict__ Wi, const float* __restrict__ ip,
    const float* __restrict__ op, const float* __restrict__ xp,
    const float* __restrict__ dtw,
    const float* __restrict__ cw, const float* __restrict__ cb,
    const float* __restrict__ db, const float* __restrict__ Dv,
    unsigned char* __restrict__ xpad,
    unsigned char* __restrict__ WiT, unsigned char* __restrict__ dtwP,
    unsigned char* __restrict__ ip4, unsigned char* __restrict__ op4,
    unsigned char* __restrict__ xp4,
    floatx2* __restrict__ cwcb, floatx2* __restrict__ dbdv)
{
    __shared__ float tbuf[64][68];
    const int fid = blockIdx.x;

    if (fid < 1264) {
        const float* src; unsigned char* dst;
        int K, N, ngK, t;
        bool isfp4;
        if (fid < 16) {
            src = Wi; dst = WiT; K = IN_D; N = DM; ngK = 4; t = fid; isfp4 = false;
        } else if (fid < 784) {
            int local = fid - 16; int l = local >> 6; t = local & 63;
            K = DM; N = 2 * DI; ngK = 4; isfp4 = true;
            src = ip + (size_t)l * K * N; dst = ip4 + (size_t)l * 131072;
        } else if (fid < 1168) {
            int local = fid - 784; int l = local >> 5; t = local & 31;
            K = DI; N = DM; ngK = 8; isfp4 = true;
            src = op + (size_t)l * K * N; dst = op4 + (size_t)l * 65536;
        } else {
            int local = fid - 1168; int l = local >> 3; t = local & 7;
            K = DI; N = XPN; ngK = 8; isfp4 = true;
            src = xp + (size_t)l * K * N; dst = xp4 + (size_t)l * 16384;
        }
        const int g = t % ngK, nb = t / ngK;
        const int k0 = g * 64, n0 = nb * 64;
        {
            const int t4 = threadIdx.x;
#pragma unroll
            for (int i = 0; i < 4; i++) {
                int fi = i * 256 + t4;           // float4 index in tile (0..1023)
                int lr = fi >> 4;                // local row 0..63
                int lc = (fi & 15) * 4;          // local col 0,4,..60
                int kk = k0 + lr, nn = n0 + lc;
                floatx4 v;
                if (kk < K && nn + 3 < N) {
                    v = *(const floatx4*)(src + (size_t)kk * N + nn);
                } else {
#pragma unroll
                    for (int j = 0; j < 4; j++)
                        v[j] = (kk < K && nn + j < N) ? src[(size_t)kk * N + nn + j] : 0.0f;
                }
                *(floatx4*)(&tbuf[lr][lc]) = v;
            }
        }
        __syncthreads();
        if (!isfp4) {
            // fp8 fragment chunk (16 cols x 64 k -> 1024 B)
            const int cbi = threadIdx.x >> 6;
            const int lane = threadIdx.x & 63;
            const int q = lane >> 4, m16 = lane & 15;
            const int chunk = (nb * 4 + cbi) * ngK + g;
            union { unsigned char b[16]; intx4 v; } buf;
#pragma unroll
            for (int sub = 0; sub < 2; sub++)
#pragma unroll
                for (int byt = 0; byt < 8; byt++) {
                    int k = sub * 32 + q * 8 + byt;
                    int n = cbi * 16 + m16;
                    buf.b[sub * 8 + byt] = f2fp8(tbuf[k][n]);
                }
            *(intx4*)(dst + (size_t)chunk * 1024 + lane * 16) = buf.v;
        } else {
            // fp4 fragment half-chunk: tile = k-group g (64 wide) of fp4 chunk kg=g>>1
            const int kg = g >> 1, half = g & 1;
            const int nkg128 = ngK >> 1;
            const int cbi = threadIdx.x >> 6;          // 0..3
            const int rem = threadIdx.x & 63;
            const int q4loc = rem >> 5;                // 0..1
            const int hb = (rem >> 4) & 1;             // 0..1
            const int m16 = rem & 15;
            const int q4 = half * 2 + q4loc;
            const int chunk = (nb * 4 + cbi) * nkg128 + kg;
            const int kb = q4loc * 32 + hb * 16;
            const int nn = cbi * 16 + m16;
            union { unsigned u[2]; long v; } buf;
#if __has_builtin(__builtin_amdgcn_cvt_scalef32_pk_fp4_f32)
            unsigned d0 = 0, d1 = 0;
            d0 = __builtin_amdgcn_cvt_scalef32_pk_fp4_f32(d0, tbuf[kb + 0][nn] * 128.0f, tbuf[kb + 1][nn] * 128.0f, 1.0f, 0);
            d0 = __builtin_amdgcn_cvt_scalef32_pk_fp4_f32(d0, tbuf[kb + 2][nn] * 128.0f, tbuf[kb + 3][nn] * 128.0f, 1.0f, 1);
            d0 = __builtin_amdgcn_cvt_scalef32_pk_fp4_f32(d0, tbuf[kb + 4][nn] * 128.0f, tbuf[kb + 5][nn] * 128.0f, 1.0f, 2);
            d0 = __builtin_amdgcn_cvt_scalef32_pk_fp4_f32(d0, tbuf[kb + 6][nn] * 128.0f, tbuf[kb + 7][nn] * 128.0f, 1.0f, 3);
            d1 = __builtin_amdgcn_cvt_scalef32_pk_fp4_f32(d1, tbuf[kb + 8][nn] * 128.0f, tbuf[kb + 9][nn] * 128.0f, 1.0f, 0);
            d1 = __builtin_amdgcn_cvt_scalef32_pk_fp4_f32(d1, tbuf[kb + 10][nn] * 128.0f, tbuf[kb + 11][nn] * 128.0f, 1.0f, 1);
            d1 = __builtin_amdgcn_cvt_scalef32_pk_fp4_f32(d1, tbuf[kb + 12][nn] * 128.0f, tbuf[kb + 13][nn] * 128.0f, 1.0f, 2);
            d1 = __builtin_amdgcn_cvt_scalef32_pk_fp4_f32(d1, tbuf[kb + 14][nn] * 128.0f, tbuf[kb + 15][nn] * 128.0f, 1.0f, 3);
            buf.u[0] = d0; buf.u[1] = d1;
#else
            union { unsigned char b[8]; long v; } bb;
#pragma unroll
            for (int bl = 0; bl < 8; bl++) {
                unsigned ob = 0;
#pragma unroll
                for (int i = 0; i < 2; i++) {
                    float v = tbuf[kb + bl * 2 + i][nn] * 128.0f;
                    ob |= f2fp4(v) << (i * 4);
                }
                bb.b[bl] = (unsigned char)ob;
            }
            buf.v = bb.v;
#endif
            *(long*)(dst + (size_t)chunk * 1024 + (q4 * 16 + m16) * 16 + hb * 8) = buf.v;
        }
    } else if (fid < 1456) {
        // dt_w [NL][16][512] -> packed fp8 fragments, K=16 padded to 32; 4 B/thread
        int gid = (fid - 1264) * 256 + threadIdx.x;   // dword index [0, 49152)
        int idx = gid * 4;                            // byte index
        int l = idx >> 14;
        int r14 = idx & 16383;
        int chunk = r14 >> 9;
        int rr = r14 & 511;
        int lane = rr >> 3, byt0 = rr & 7;            // byt0 in {0,4}
        int q = lane >> 4, m16 = lane & 15;
        int col = chunk * 16 + m16;
        float v[4];
#pragma unroll
        for (int j = 0; j < 4; j++) {
            int k = q * 8 + byt0 + j;
            v[j] = (k < DTR) ? dtw[(size_t)l * DTR * DI + (size_t)k * DI + col] : 0.0f;
        }
        *(unsigned*)(dtwP + idx) = pk4fp8(v[0], v[1], v[2], v[3]);
    } else if (fid < 1480) {
        int idx = (fid - 1456) * 256 + threadIdx.x;
        floatx2 v; v.x = cw[(size_t)idx * 4 + 3]; v.y = cb[idx];
        cwcb[idx] = v;
    } else if (fid < 1504) {
        int idx = (fid - 1480) * 256 + threadIdx.x;
        floatx2 v; v.x = db[idx]; v.y = Dv[idx];
        dbdv[idx] = v;
    } else {
        // x [4096 x 230] fp32 -> xpad [4096 x 256] fp8; 4 B/thread
        int gid = (fid - 1504) * 256 + threadIdx.x;   // dword index [0, 262144)
        int r = gid >> 6, c4 = (gid & 63) * 4;
        float v[4];
#pragma unroll
        for (int j = 0; j < 4; j++) {
            int k = c4 + j;
            v[j] = (k < IN_D) ? x[(size_t)r * IN_D + k] : 0.0f;
        }
        *(unsigned*)(xpad + (size_t)gid * 4) = pk4fp8(v[0], v[1], v[2], v[3]);
    }
}

// ---------- the whole network, fused: 256 wgs x 16 rows, 1024 threads ----------
// OPERAND-SWAPPED MFMAs: A = weights (fp4 via cbsz=4 / fp8), B = activations (fp8).
// R9 = exact R6 structure (proven best: mamba 77.6us) + packed fp8 decode.
// Closed-off levers (evidence): min-waves clamp spills (R1, WRITE 57MB);
// 8-row blocks duplicate M=16 work 2x (R2); cross-layer ping-pong prefetch
// spills (R3); a2[12] whole-layer hoist spills (R7, arch-VGPR hard cap 64 =
// unified 128/wave split 64V+64A at 4 waves/SIMD); S2+S3 merge net-negative
// even spill-free (R8: 3x redundant MFMA + in-stage cold loads > 1 barrier+dbls).
// Kept: single-set layer-top hoist of w3/a4 (R6: 85.7 -> 77.6us, fits 64 regs).
__global__ __launch_bounds__(1024) void mamba_all(
    const unsigned char* __restrict__ xpad, const unsigned char* __restrict__ WiT,
    const float* __restrict__ bi,
    const unsigned char* __restrict__ ip4, const unsigned char* __restrict__ op4,
    const unsigned char* __restrict__ xp4, const unsigned char* __restrict__ dtwP,
    const floatx2* __restrict__ cwcb, const floatx2* __restrict__ dbdv,
    const float* __restrict__ Wo, const float* __restrict__ bo,
    float* __restrict__ out)
{
    __shared__ unsigned char hs[16 * HB];
    __shared__ unsigned char xcs[16 * XB];
    __shared__ unsigned char szs[16 * XB];
    __shared__ float dbls[16 * 68];

    const int tid = threadIdx.x;
    const int w = tid >> 6, lane = tid & 63;
    const int q = lane >> 4, m16 = lane & 15;
    const int rb = blockIdx.x * 16;
    const long2v z2 = (long2v){0, 0};

    // stage 0: h = xpad @ Wi + bi  (A = Wi fragments, B = batch rows)
    {
        floatx4 a0 = (floatx4){0.f, 0.f, 0.f, 0.f};
        floatx4 a1 = (floatx4){0.f, 0.f, 0.f, 0.f};
        const unsigned char* Bp = xpad + (size_t)(rb + m16) * DM + q * 8;
        const unsigned char* Ap = WiT + (size_t)(w * 4) * 1024 + lane * 16;
#pragma unroll
        for (int g = 0; g < 4; g++) {
            long2v a = *(const long2v*)(Ap + g * 1024);
            long bv0 = *(const long*)(Bp + (g * 2) * 32);
            long bv1 = *(const long*)(Bp + (g * 2 + 1) * 32);
            a0 = __builtin_amdgcn_mfma_f32_16x16x32_fp8_fp8(a.x, bv0, a0, 0, 0, 0);
            a1 = __builtin_amdgcn_mfma_f32_16x16x32_fp8_fp8(a.y, bv1, a1, 0, 0, 0);
        }
        a0 = a0 + a1;
        floatx4 b4 = *(const floatx4*)(bi + w * 16 + q * 4);
        *(unsigned*)(hs + m16 * HB + w * 16 + q * 4) =
            pk4fp8(a0[0] + b4[0], a0[1] + b4[1], a0[2] + b4[2], a0[3] + b4[3]);
    }
    __syncthreads();

    for (int l = 0; l < NL; l++) {
        const unsigned char* ipw = ip4 + (size_t)l * 131072;
        const unsigned char* xpw = xp4 + (size_t)l * 16384;
        const unsigned char* opw = op4 + (size_t)l * 65536;
        const unsigned char* dwp = dtwP + (size_t)l * 16384;
        const floatx2* cc = cwcb + (size_t)l * DI;
        const floatx2* dd = dbdv + (size_t)l * DI;

        // ---- layer-top hoisted loads: stage-2/3/4 fragments (one L2 exposure) ----
        long2v a2[4];
        if (w < 4) {
            const unsigned char* Ap2 = xpw + (size_t)(w * 4) * 1024 + lane * 16;
#pragma unroll
            for (int i = 0; i < 4; i++) a2[i] = *(const long2v*)(Ap2 + (size_t)i * 1024);
        }
        long w3a, w3b;
        {
            const unsigned char* Wp = dwp + (size_t)(w * 2) * 512 + lane * 8;
            w3a = *(const long*)(Wp);
            w3b = *(const long*)(Wp + 512);
        }
        long2v a4[4];
        {
            const unsigned char* Ap4 = opw + (size_t)(w * 4) * 1024 + lane * 16;
#pragma unroll
            for (int i = 0; i < 4; i++) a4[i] = *(const long2v*)(Ap4 + (size_t)i * 1024);
        }

        // stage 1: xz = h @ in_proj  (wave w: cols w*64..+63; K=256 -> 2 kg of 128)
        {
            floatx4 acc[4];
#pragma unroll
            for (int t = 0; t < 4; t++) acc[t] = (floatx4){0.f, 0.f, 0.f, 0.f};
            const unsigned char* Ap = ipw + (size_t)(w * 8) * 1024 + lane * 16;
            const unsigned char* Br = hs + m16 * HB + q * 32;
#pragma unroll
            for (int kg = 0; kg < 2; kg++) {
                union { long2v h[2]; intx8 v; } bv;
                bv.h[0] = *(const long2v*)(Br + kg * 128);
                bv.h[1] = *(const long2v*)(Br + kg * 128 + 16);
#pragma unroll
                for (int t = 0; t < 4; t++) {
                    union { long2v h[2]; intx8 v; } av;
                    av.h[0] = *(const long2v*)(Ap + (size_t)(t * 2 + kg) * 1024);
                    av.h[1] = z2;
                    acc[t] = __builtin_amdgcn_mfma_scale_f32_16x16x128_f8f6f4(
                        av.v, bv.v, acc[t], 4, 0, 0, 120, 0, 127);
                }
            }
            if (w < 8) {
#pragma unroll
                for (int t = 0; t < 4; t++) {
                    int colb = w * 64 + t * 16 + q * 4;
                    floatx4 cA = *(const floatx4*)(cc + colb);
                    floatx4 cB = *(const floatx4*)(cc + colb + 2);
                    float v0 = silu_f(acc[t][0] * cA[0] + cA[1]);
                    float v1 = silu_f(acc[t][1] * cA[2] + cA[3]);
                    float v2 = silu_f(acc[t][2] * cB[0] + cB[1]);
                    float v3 = silu_f(acc[t][3] * cB[2] + cB[3]);
                    *(unsigned*)(xcs + m16 * XB + colb) = pk4fp8(v0, v1, v2, v3);
                }
            } else {
#pragma unroll
                for (int t = 0; t < 4; t++) {
                    int colb = (w - 8) * 64 + t * 16 + q * 4;
                    *(unsigned*)(szs + m16 * XB + colb) =
                        pk4fp8(silu_f(acc[t][0]), silu_f(acc[t][1]),
                               silu_f(acc[t][2]), silu_f(acc[t][3]));
                }
            }
        }
        __syncthreads();

        // stage 2: dbl = xc @ x_proj  (waves 0..3: col-blk w; K=512 -> 4 kg)
        if (w < 4) {
            floatx4 acc = (floatx4){0.f, 0.f, 0.f, 0.f};
            const unsigned char* Br = xcs + m16 * XB + q * 32;
#pragma unroll
            for (int kg = 0; kg < 4; kg++) {
                union { long2v h[2]; intx8 v; } bv;
                bv.h[0] = *(const long2v*)(Br + kg * 128);
                bv.h[1] = *(const long2v*)(Br + kg * 128 + 16);
                union { long2v h[2]; intx8 v; } av;
                av.h[0] = a2[kg];
                av.h[1] = z2;
                acc = __builtin_amdgcn_mfma_scale_f32_16x16x128_f8f6f4(
                    av.v, bv.v, acc, 4, 0, 0, 120, 0, 127);
            }
            *(floatx4*)(&dbls[m16 * 68 + w * 16 + q * 4]) = acc;
        }
        __syncthreads();

        // stage 3 (all waves): bc dot, dt MFMA (A = dt_w frags, B = dt input), gate
        {
            const int cb0 = w * 32 + q * 4;

            // p = B.C per batch row (dbls layout [batch][col])
            const int brow = lane >> 2, bj = lane & 3;
            const float* dr0 = &dbls[brow * 68 + DTR];
            float p = dr0[bj]      * dr0[DST + bj]
                    + dr0[bj + 4]  * dr0[DST + bj + 4]
                    + dr0[bj + 8]  * dr0[DST + bj + 8]
                    + dr0[bj + 12] * dr0[DST + bj + 12];
            p += __shfl_xor(p, 1);
            p += __shfl_xor(p, 2);
            float bcv = __shfl(p, m16 * 4);        // bc for THIS thread's batch row

            // dt-input B-fragment: col = batch m16, k = q*8.. (real k < 16)
            long bfrag = 0;
            if (q < 2) {
                const float* dr = &dbls[m16 * 68 + q * 8];
                union { unsigned u[2]; long l; } uv;
                uv.u[0] = pk4fp8(dr[0], dr[1], dr[2], dr[3]);
                uv.u[1] = pk4fp8(dr[4], dr[5], dr[6], dr[7]);
                bfrag = uv.l;
            }

            floatx4 dA = *(const floatx4*)(dd + cb0);
            floatx4 dB = *(const floatx4*)(dd + cb0 + 2);
            floatx4 dC = *(const floatx4*)(dd + cb0 + 16);
            floatx4 dD = *(const floatx4*)(dd + cb0 + 18);
            floatx4 d0v = (floatx4){dA[0], dA[2], dB[0], dB[2]};   // dt_b
            floatx4 d1v = (floatx4){dC[0], dC[2], dD[0], dD[2]};
            floatx4 Dv0 = (floatx4){dA[1], dA[3], dB[1], dB[3]};   // D
            floatx4 Dv1 = (floatx4){dC[1], dC[3], dD[1], dD[3]};
            d0v = __builtin_amdgcn_mfma_f32_16x16x32_fp8_fp8(w3a, bfrag, d0v, 0, 0, 0);
            d1v = __builtin_amdgcn_mfma_f32_16x16x32_fp8_fp8(w3b, bfrag, d1v, 0, 0, 0);

            const int off = m16 * XB + cb0;
            unsigned xw0 = *(const unsigned*)(xcs + off);
            unsigned zw0 = *(const unsigned*)(szs + off);
            unsigned xw1 = *(const unsigned*)(xcs + off + 16);
            unsigned zw1 = *(const unsigned*)(szs + off + 16);
            float xf0[4], zf0[4], xf1[4], zf1[4];
            up4fp8(xw0, xf0); up4fp8(zw0, zf0);
            up4fp8(xw1, xf1); up4fp8(zw1, zf1);
            float y0[4], y1[4];
#pragma unroll
            for (int r = 0; r < 4; r++) {
                y0[r] = (softplus_f(d0v[r]) * bcv + Dv0[r]) * xf0[r] * zf0[r];
                y1[r] = (softplus_f(d1v[r]) * bcv + Dv1[r]) * xf1[r] * zf1[r];
            }
            *(unsigned*)(xcs + off)      = pk4fp8(y0[0], y0[1], y0[2], y0[3]);
            *(unsigned*)(xcs + off + 16) = pk4fp8(y1[0], y1[1], y1[2], y1[3]);
        }
        __syncthreads();

        // stage 4: h = y @ out_proj  (wave w: col-blk w; K=512 -> 4 kg)
        {
            floatx4 acc = (floatx4){0.f, 0.f, 0.f, 0.f};
            const unsigned char* Br = xcs + m16 * XB + q * 32;
#pragma unroll
            for (int kg = 0; kg < 4; kg++) {
                union { long2v h[2]; intx8 v; } bv;
                bv.h[0] = *(const long2v*)(Br + kg * 128);
                bv.h[1] = *(const long2v*)(Br + kg * 128 + 16);
                union { long2v h[2]; intx8 v; } av;
                av.h[0] = a4[kg];
                av.h[1] = z2;
                acc = __builtin_amdgcn_mfma_scale_f32_16x16x128_f8f6f4(
                    av.v, bv.v, acc, 4, 0, 0, 120, 0, 127);
            }
            *(unsigned*)(hs + m16 * HB + w * 16 + q * 4) =
                pk4fp8(acc[0], acc[1], acc[2], acc[3]);
        }
        __syncthreads();
    }

    // final: wave w reduces row w
    {
        unsigned hw = *(const unsigned*)(hs + w * HB + lane * 4);
        floatx4 w4 = *(const floatx4*)(Wo + lane * 4);
        float hf[4];
        up4fp8(hw, hf);
        float s = hf[0] * w4[0] + hf[1] * w4[1] + hf[2] * w4[2] + hf[3] * w4[3];
#pragma unroll
        for (int off = 32; off > 0; off >>= 1) s += __shfl_down(s, off);
        if (lane == 0) out[rb + w] = s + bo[0];
    }
}

extern "C" void kernel_launch(void* const* d_in, const int* in_sizes, int n_in,
                              void* d_out, int out_size, void* d_ws, size_t ws_size,
                              hipStream_t stream)
{
    const float* x       = (const float*)d_in[0];
    const float* Wi      = (const float*)d_in[1];
    const float* bi      = (const float*)d_in[2];
    const float* in_proj = (const float*)d_in[3];
    const float* conv_w  = (const float*)d_in[4];
    const float* conv_b  = (const float*)d_in[5];
    const float* x_proj  = (const float*)d_in[6];
    const float* dt_w    = (const float*)d_in[7];
    const float* dt_b    = (const float*)d_in[8];
    // d_in[9] = A_log: dead (L==1, h0==0)
    const float* Dp      = (const float*)d_in[10];
    const float* out_pw  = (const float*)d_in[11];
    const float* Wo      = (const float*)d_in[12];
    const float* bo      = (const float*)d_in[13];

    unsigned char* ws = (unsigned char*)d_ws;
    unsigned char* xpad = ws;                              // 1 MB
    unsigned char* WiT  = xpad + (size_t)NB * DM;          // 64 KB fp8
    unsigned char* dtwP = WiT + (size_t)DM * DM;           // 12*16 KB fp8
    floatx2* cwcb = (floatx2*)(dtwP + (size_t)NL * 16384); // 12*512 float2
    floatx2* dbdv = cwcb + (size_t)NL * DI;                // 12*512 float2
    unsigned char* ip4 = (unsigned char*)(dbdv + (size_t)NL * DI); // 12*128 KB fp4
    unsigned char* op4 = ip4 + (size_t)NL * 131072;        // 12*64 KB fp4
    unsigned char* xp4 = op4 + (size_t)NL * 65536;         // 12*16 KB fp4

    pack_all<<<dim3(2528), dim3(256), 0, stream>>>(
        x, Wi, in_proj, out_pw, x_proj, dt_w, conv_w, conv_b, dt_b, Dp,
        xpad, WiT, dtwP, ip4, op4, xp4, cwcb, dbdv);

    mamba_all<<<dim3(NB / 16), dim3(1024), 0, stream>>>(
        xpad, WiT, bi, ip4, op4, xp4, dtwP,
        cwcb, dbdv, Wo, bo, (float*)d_out);
}